// Round 12
// baseline (224.125 us; speedup 1.0000x reference)
//
#include <hip/hip_runtime.h>
#include <hip/hip_bf16.h>
#include <math.h>

#define N_NODES 100000
#define N_EDGES 600000
#define F1 128   // conv1 width
#define F2 64    // conv2 width

#define DEG_BLOCKS   ((N_EDGES + 255) / 256)           // 2344
#define CONVW_ELEMS  (128 * 128 + 128 * 64)
#define CONVW_BLOCKS ((CONVW_ELEMS + 255) / 256)       // 96
#define XB_BLOCKS    ((N_NODES * 128) / 2048)          // 6250 (exact)
#define MG_BLOCKS    ((N_NODES + 127) / 128)           // 782 (128 rows/block)

typedef __attribute__((ext_vector_type(8))) short bf16x8;
typedef __attribute__((ext_vector_type(4))) float f32x4;

__device__ inline short bfbits(float x) {
    __hip_bfloat16 h = __float2bfloat16(x);
    return *reinterpret_cast<short*>(&h);
}
__device__ inline float bf2f(short u) {
    unsigned int x = ((unsigned int)(unsigned short)u) << 16;
    return __uint_as_float(x);
}

// ---------------- fused: degree || W convert || X convert (all independent) ----------------

__global__ __launch_bounds__(256) void dc_kernel(const int* __restrict__ dst, int* __restrict__ deg,
                                                 const float* __restrict__ W1, const float* __restrict__ W2,
                                                 unsigned short* __restrict__ Wt1, unsigned short* __restrict__ Wt2,
                                                 const float* __restrict__ X, unsigned short* __restrict__ Xb) {
    const int b = blockIdx.x;
    if (b < DEG_BLOCKS) {
        int e = b * 256 + threadIdx.x;
        if (e < N_EDGES) atomicAdd(&deg[dst[e]], 1);
    } else if (b < DEG_BLOCKS + CONVW_BLOCKS) {
        int i = (b - DEG_BLOCKS) * 256 + threadIdx.x;
        if (i < 128 * 128) {
            int k = i / 128, n = i % 128;
            Wt1[n * 128 + k] = (unsigned short)bfbits(W1[i]);
        } else if (i < CONVW_ELEMS) {
            int j = i - 128 * 128;
            int k = j / 64, n = j % 64;
            Wt2[n * 128 + k] = (unsigned short)bfbits(W2[j]);
        }
    } else {
        // coalesced fp32 -> bf16 conversion of X (8 elems/thread)
        const size_t i = ((size_t)(b - DEG_BLOCKS - CONVW_BLOCKS) * 256 + threadIdx.x) * 8;
        const float4 v0 = *(const float4*)(X + i);
        const float4 v1 = *(const float4*)(X + i + 4);
        bf16x8 t;
        t[0] = bfbits(v0.x); t[1] = bfbits(v0.y); t[2] = bfbits(v0.z); t[3] = bfbits(v0.w);
        t[4] = bfbits(v1.x); t[5] = bfbits(v1.y); t[6] = bfbits(v1.z); t[7] = bfbits(v1.w);
        *(bf16x8*)(Xb + i) = t;
    }
}

// ---------------- fused: dinv + region alloc (wave scan + one atomic) + cur init ----------

__global__ void prep_kernel(const int* __restrict__ deg, int* __restrict__ counter,
                            float* __restrict__ dinv, int* __restrict__ off,
                            int* __restrict__ cur) {
    int i = blockIdx.x * blockDim.x + threadIdx.x;
    int d = (i < N_NODES) ? deg[i] : 0;
    if (i < N_NODES) dinv[i] = rsqrtf((float)(d + 1));   // +1 self-loop
    int incl = d;
    #pragma unroll
    for (int o = 1; o < 64; o <<= 1) {
        int v = __shfl_up(incl, o);
        if ((threadIdx.x & 63) >= o) incl += v;
    }
    int base = 0;
    if ((threadIdx.x & 63) == 63) base = atomicAdd(counter, incl);
    base = __shfl(base, 63);
    if (i < N_NODES) {
        int o = base + incl - d;
        off[i] = o;
        cur[i] = o;
    }
}

// ---------------- GEMM body: C^T operand swap, 2 row-tiles per wave (32 rows) ----------------
// bf16 in, bf16 out; B-fragment reused across both row-tiles.

template<int HO>
__device__ __forceinline__ void gemm_body(int blk, const unsigned short* __restrict__ Xb,
                                          const unsigned short* __restrict__ Wt,
                                          unsigned short* __restrict__ out) {
    constexpr int NT = HO / 16;
    const int tid = threadIdx.x;
    const int wid = tid >> 6;
    const int l   = tid & 63;
    const int l16 = l & 15;
    const int kg  = l >> 4;          // 0..3

    const int row0 = blk * 128 + wid * 32 + l16;
    const int row1 = row0 + 16;
    const int r0c = (row0 < N_NODES) ? row0 : (N_NODES - 1);
    const int r1c = (row1 < N_NODES) ? row1 : (N_NODES - 1);

    bf16x8 a0[4], a1[4];
    const unsigned short* x0 = Xb + (size_t)r0c * 128 + kg * 8;
    const unsigned short* x1 = Xb + (size_t)r1c * 128 + kg * 8;
    #pragma unroll
    for (int ks = 0; ks < 4; ks++) {
        a0[ks] = *(const bf16x8*)(x0 + ks * 32);
        a1[ks] = *(const bf16x8*)(x1 + ks * 32);
    }

    f32x4 acc0[NT], acc1[NT];
    #pragma unroll
    for (int t = 0; t < NT; t++) {
        acc0[t] = (f32x4){0.f, 0.f, 0.f, 0.f};
        acc1[t] = (f32x4){0.f, 0.f, 0.f, 0.f};
    }

    #pragma unroll
    for (int t = 0; t < NT; t++) {
        const unsigned short* wp = Wt + (size_t)(t * 16 + l16) * 128 + kg * 8;
        #pragma unroll
        for (int ks = 0; ks < 4; ks++) {
            bf16x8 bb = *(const bf16x8*)(wp + ks * 32);
            acc0[t] = __builtin_amdgcn_mfma_f32_16x16x32_bf16(bb, a0[ks], acc0[t], 0, 0, 0);
            acc1[t] = __builtin_amdgcn_mfma_f32_16x16x32_bf16(bb, a1[ks], acc1[t], 0, 0, 0);
        }
    }

    // C^T: thread owns rows row0/row1, cols {t*16 + kg*4 + r}
    if (row0 < N_NODES) {
        #pragma unroll
        for (int t = 0; t < NT; t++) {
            short4 pk;
            pk.x = bfbits(acc0[t][0]); pk.y = bfbits(acc0[t][1]);
            pk.z = bfbits(acc0[t][2]); pk.w = bfbits(acc0[t][3]);
            *(short4*)(out + (size_t)row0 * HO + t * 16 + kg * 4) = pk;
        }
    }
    if (row1 < N_NODES) {
        #pragma unroll
        for (int t = 0; t < NT; t++) {
            short4 pk;
            pk.x = bfbits(acc1[t][0]); pk.y = bfbits(acc1[t][1]);
            pk.z = bfbits(acc1[t][2]); pk.w = bfbits(acc1[t][3]);
            *(short4*)(out + (size_t)row1 * HO + t * 16 + kg * 4) = pk;
        }
    }
}

// ---------------- fused: MFMA GEMM layer-1 || CSR fill ----------------

__global__ __launch_bounds__(256) void mf_kernel(const unsigned short* __restrict__ Xb,
                                                 const unsigned short* __restrict__ Wt,
                                                 unsigned short* __restrict__ out,
                                                 const int* __restrict__ src, const int* __restrict__ dst,
                                                 int* __restrict__ cur, int* __restrict__ csr_src) {
    if (blockIdx.x >= MG_BLOCKS) {
        int e = (blockIdx.x - MG_BLOCKS) * 256 + threadIdx.x;
        if (e < N_EDGES) {
            int s = src[e], d = dst[e];
            int pos = atomicAdd(&cur[d], 1);
            csr_src[pos] = s;
        }
        return;
    }
    gemm_body<128>(blockIdx.x, Xb, Wt, out);
}

// ---------------- MFMA GEMM (layer 2): out[N,64] ----------------

__global__ __launch_bounds__(256) void mgemm2_kernel(const unsigned short* __restrict__ Xb,
                                                     const unsigned short* __restrict__ Wt,
                                                     unsigned short* __restrict__ out) {
    gemm_body<64>(blockIdx.x, Xb, Wt, out);
}

// ---------------- fused aggregation (bf16 in/out, f32 accum), batch-4 ----------------

template<int F>
__global__ __launch_bounds__(256) void gather_kernel(const unsigned short* __restrict__ xw,
                                                     const float* __restrict__ dinv,
                                                     const int* __restrict__ off,
                                                     const int* __restrict__ deg,
                                                     const int* __restrict__ csr_src,
                                                     const float* __restrict__ bias,
                                                     unsigned short* __restrict__ h) {
    constexpr int LANES = F / 8;        // bf16x8 lanes per node: 16 or 8
    constexpr int NPB = 256 / LANES;
    const int n = blockIdx.x * NPB + threadIdx.x / LANES;
    if (n >= N_NODES) return;
    const int c = threadIdx.x % LANES;

    const float dn = dinv[n];
    float acc[8];
    {
        const bf16x8 v = *(const bf16x8*)(xw + (size_t)n * F + c * 8);
        const float sl = dn * dn;
        #pragma unroll
        for (int i = 0; i < 8; i++) acc[i] = bf2f(v[i]) * sl;
    }

    const int e0 = off[n];
    const int e1 = e0 + deg[n];
    for (int j = e0; j < e1; j += 4) {
        int s[4];
        #pragma unroll
        for (int u = 0; u < 4; u++) {
            const int jj = j + u;
            const int jc = (jj < e1) ? jj : (e1 - 1);
            s[u] = csr_src[jc];
        }
        float w[4]; bf16x8 v[4];
        #pragma unroll
        for (int u = 0; u < 4; u++) {
            w[u] = (j + u < e1) ? dinv[s[u]] * dn : 0.f;
            v[u] = *(const bf16x8*)(xw + (size_t)s[u] * F + c * 8);
        }
        #pragma unroll
        for (int u = 0; u < 4; u++) {
            #pragma unroll
            for (int i = 0; i < 8; i++) acc[i] += bf2f(v[u][i]) * w[u];
        }
    }

    bf16x8 o;
    #pragma unroll
    for (int i = 0; i < 8; i++) o[i] = bfbits(fmaxf(acc[i] + bias[c * 8 + i], 0.f));
    *(bf16x8*)(h + (size_t)n * F + c * 8) = o;
}

// ---------------- head: gelu(h2 @ Wh1 + bh1) @ Wh2 + bh2 -> sigmoid ----------------

__global__ __launch_bounds__(256) void head_kernel(const unsigned short* __restrict__ h2,
                                                   const float* __restrict__ Wh1,
                                                   const float* __restrict__ bh1,
                                                   const float* __restrict__ Wh2,
                                                   const float* __restrict__ bh2,
                                                   float* __restrict__ out) {
    __shared__ float W1s[64 * 16];
    __shared__ float h2s[16 * 64];
    __shared__ float W2s[16];
    __shared__ float b1s[16];
    const int tid = threadIdx.x;
    const int node0 = blockIdx.x * 16;

    ((float4*)W1s)[tid] = ((const float4*)Wh1)[tid];
    if (tid < 16) { W2s[tid] = Wh2[tid]; b1s[tid] = bh1[tid]; }
    if (tid < 128) {                       // 16 nodes x 8 bf16x8-chunks
        int node = node0 + tid / 8;
        int ch = tid % 8;
        if (node < N_NODES) {
            bf16x8 v = *(const bf16x8*)(h2 + (size_t)node * 64 + ch * 8);
            #pragma unroll
            for (int i = 0; i < 8; i++) h2s[(tid / 8) * 64 + ch * 8 + i] = bf2f(v[i]);
        } else {
            #pragma unroll
            for (int i = 0; i < 8; i++) h2s[(tid / 8) * 64 + ch * 8 + i] = 0.f;
        }
    }
    __syncthreads();

    const int l  = tid & 15;
    const int nl = tid >> 4;
    const int node = node0 + nl;

    float s = b1s[l];
    #pragma unroll 8
    for (int k = 0; k < 64; k++)
        s += h2s[nl * 64 + k] * W1s[k * 16 + l];
    float g = 0.5f * s * (1.f + erff(s * 0.70710678118654752f));
    float p = g * W2s[l];
    p += __shfl_xor(p, 1);
    p += __shfl_xor(p, 2);
    p += __shfl_xor(p, 4);
    p += __shfl_xor(p, 8);
    if (l == 0 && node < N_NODES) {
        float z = p + bh2[0];
        out[node] = 1.f / (1.f + expf(-z));
    }
}

// ---------------- launch ----------------

extern "C" void kernel_launch(void* const* d_in, const int* in_sizes, int n_in,
                              void* d_out, int out_size, void* d_ws, size_t ws_size,
                              hipStream_t stream) {
    const float* x   = (const float*)d_in[0];
    const int*   ei  = (const int*)d_in[1];
    const float* W1  = (const float*)d_in[2];
    const float* b1  = (const float*)d_in[3];
    const float* W2  = (const float*)d_in[4];
    const float* b2  = (const float*)d_in[5];
    const float* Wh1 = (const float*)d_in[6];
    const float* bh1 = (const float*)d_in[7];
    const float* Wh2 = (const float*)d_in[8];
    const float* bh2 = (const float*)d_in[9];
    float* out = (float*)d_out;

    const int* srcA = ei;             // edge_index[0]
    const int* dstA = ei + N_EDGES;   // edge_index[1]

    char* ws = (char*)d_ws;
    const size_t MB = 1u << 20;
    float* dinv    = (float*)(ws);                    // N f32
    int*   deg     = (int*)  (ws + MB / 2);           // N i32 (+1 counter)
    int*   counter = deg + N_NODES;                   // 1 i32
    int*   off     = (int*)  (ws + MB);               // N i32
    int*   cur     = (int*)  (ws + MB + MB / 2);      // N i32
    int*   csr_src = (int*)  (ws + 2 * MB);           // E i32 (2.4MB)
    unsigned short* Wt1 = (unsigned short*)(ws + 7 * MB);            // 128x128 bf16
    unsigned short* Wt2 = Wt1 + 128 * 128;                           // 64x128 bf16
    unsigned short* bufA = (unsigned short*)(ws + 8 * MB);           // xw1 (N x 128 bf16, 25.6MB)
    unsigned short* bufB = (unsigned short*)(ws + 34 * MB);          // h1  (N x 128 bf16)
    unsigned short* Xb   = (unsigned short*)(ws + 60 * MB);          // X bf16 (N x 128, 25.6MB)
    unsigned short* xw2  = bufA;                                     // N x 64 bf16
    unsigned short* h2   = bufA + (size_t)N_NODES * F2;              // N x 64 bf16

    // zero deg+counter; (deg || convw || convX); prep; (mgemm1 || fill)
    hipMemsetAsync(deg, 0, (N_NODES + 1) * sizeof(int), stream);
    dc_kernel<<<DEG_BLOCKS + CONVW_BLOCKS + XB_BLOCKS, 256, 0, stream>>>(
        dstA, deg, W1, W2, Wt1, Wt2, x, Xb);
    prep_kernel<<<(N_NODES + 255) / 256, 256, 0, stream>>>(deg, counter, dinv, off, cur);
    mf_kernel<<<MG_BLOCKS + DEG_BLOCKS, 256, 0, stream>>>(Xb, Wt1, bufA, srcA, dstA, cur, csr_src);

    // layer 1 aggregation
    gather_kernel<128><<<(N_NODES * 16 + 255) / 256, 256, 0, stream>>>(bufA, dinv, off, deg, csr_src, b1, bufB);

    // layer 2
    mgemm2_kernel<<<MG_BLOCKS, 256, 0, stream>>>(bufB, Wt2, xw2);
    gather_kernel<64><<<(N_NODES * 8 + 255) / 256, 256, 0, stream>>>(xw2, dinv, off, deg, csr_src, b2, h2);

    // head
    head_kernel<<<(N_NODES + 15) / 16, 256, 0, stream>>>(h2, Wh1, bh1, Wh2, bh2, out);
}

// Round 13
// 221.325 us; speedup vs baseline: 1.0127x; 1.0127x over previous
//
#include <hip/hip_runtime.h>
#include <hip/hip_bf16.h>
#include <math.h>

#define N_NODES 100000
#define N_EDGES 600000
#define F1 128   // conv1 width
#define F2 64    // conv2 width

#define DEG_BLOCKS   ((N_EDGES + 255) / 256)           // 2344
#define CONVW_ELEMS  (128 * 128 + 128 * 64)
#define CONVW_BLOCKS ((CONVW_ELEMS + 255) / 256)       // 96
#define XB_BLOCKS    ((N_NODES * 128) / 2048)          // 6250 (exact)
#define MG1_BLOCKS   ((N_NODES + 63) / 64)             // 1563 (64 rows/block)
#define FILL_BLOCKS  ((N_EDGES + 1023) / 1024)         // 586 (4 edges/thread)

typedef __attribute__((ext_vector_type(8))) short bf16x8;
typedef __attribute__((ext_vector_type(4))) float f32x4;

__device__ inline short bfbits(float x) {
    __hip_bfloat16 h = __float2bfloat16(x);
    return *reinterpret_cast<short*>(&h);
}
__device__ inline float bf2f(short u) {
    unsigned int x = ((unsigned int)(unsigned short)u) << 16;
    return __uint_as_float(x);
}

// ---------------- fused: degree || W convert || X convert (all independent) ----------------

__global__ __launch_bounds__(256) void dc_kernel(const int* __restrict__ dst, int* __restrict__ deg,
                                                 const float* __restrict__ W1, const float* __restrict__ W2,
                                                 unsigned short* __restrict__ Wt1, unsigned short* __restrict__ Wt2,
                                                 const float* __restrict__ X, unsigned short* __restrict__ Xb) {
    const int b = blockIdx.x;
    if (b < DEG_BLOCKS) {
        int e = b * 256 + threadIdx.x;
        if (e < N_EDGES) atomicAdd(&deg[dst[e]], 1);
    } else if (b < DEG_BLOCKS + CONVW_BLOCKS) {
        int i = (b - DEG_BLOCKS) * 256 + threadIdx.x;
        if (i < 128 * 128) {
            int k = i / 128, n = i % 128;
            Wt1[n * 128 + k] = (unsigned short)bfbits(W1[i]);
        } else if (i < CONVW_ELEMS) {
            int j = i - 128 * 128;
            int k = j / 64, n = j % 64;
            Wt2[n * 128 + k] = (unsigned short)bfbits(W2[j]);
        }
    } else {
        // coalesced fp32 -> bf16 conversion of X (8 elems/thread)
        const size_t i = ((size_t)(b - DEG_BLOCKS - CONVW_BLOCKS) * 256 + threadIdx.x) * 8;
        const float4 v0 = *(const float4*)(X + i);
        const float4 v1 = *(const float4*)(X + i + 4);
        bf16x8 t;
        t[0] = bfbits(v0.x); t[1] = bfbits(v0.y); t[2] = bfbits(v0.z); t[3] = bfbits(v0.w);
        t[4] = bfbits(v1.x); t[5] = bfbits(v1.y); t[6] = bfbits(v1.z); t[7] = bfbits(v1.w);
        *(bf16x8*)(Xb + i) = t;
    }
}

// ---------------- fused: dinv + region alloc (wave scan + one atomic) + cur init ----------

__global__ void prep_kernel(const int* __restrict__ deg, int* __restrict__ counter,
                            float* __restrict__ dinv, int* __restrict__ off,
                            int* __restrict__ cur) {
    int i = blockIdx.x * blockDim.x + threadIdx.x;
    int d = (i < N_NODES) ? deg[i] : 0;
    if (i < N_NODES) dinv[i] = rsqrtf((float)(d + 1));   // +1 self-loop
    int incl = d;
    #pragma unroll
    for (int o = 1; o < 64; o <<= 1) {
        int v = __shfl_up(incl, o);
        if ((threadIdx.x & 63) >= o) incl += v;
    }
    int base = 0;
    if ((threadIdx.x & 63) == 63) base = atomicAdd(counter, incl);
    base = __shfl(base, 63);
    if (i < N_NODES) {
        int o = base + incl - d;
        off[i] = o;
        cur[i] = o;
    }
}

// ---------------- GEMM body: C^T operand swap, 1 row-tile/wave, bf16 in/out ----------------
// A 16x16x32 layout: A[m=l&15][k=(l>>4)*8+j]; swap -> each thread owns one X-row,
// 4 consecutive cols per tile -> packed 8B stores.

template<int HO>
__device__ __forceinline__ void gemm_body(int blk, const unsigned short* __restrict__ Xb,
                                          const unsigned short* __restrict__ Wt,
                                          unsigned short* __restrict__ out) {
    constexpr int NT = HO / 16;
    const int tid = threadIdx.x;
    const int wid = tid >> 6;
    const int l   = tid & 63;
    const int l16 = l & 15;
    const int kg  = l >> 4;          // 0..3

    const int row = blk * 64 + wid * 16 + l16;
    const int rowc = (row < N_NODES) ? row : (N_NODES - 1);

    bf16x8 a[4];
    const unsigned short* xb = Xb + (size_t)rowc * 128 + kg * 8;
    #pragma unroll
    for (int ks = 0; ks < 4; ks++) a[ks] = *(const bf16x8*)(xb + ks * 32);

    f32x4 acc[NT];
    #pragma unroll
    for (int t = 0; t < NT; t++) acc[t] = (f32x4){0.f, 0.f, 0.f, 0.f};

    #pragma unroll
    for (int t = 0; t < NT; t++) {
        const unsigned short* wp = Wt + (size_t)(t * 16 + l16) * 128 + kg * 8;
        #pragma unroll
        for (int ks = 0; ks < 4; ks++) {
            bf16x8 bb = *(const bf16x8*)(wp + ks * 32);
            acc[t] = __builtin_amdgcn_mfma_f32_16x16x32_bf16(bb, a[ks], acc[t], 0, 0, 0);
        }
    }

    if (row < N_NODES) {
        #pragma unroll
        for (int t = 0; t < NT; t++) {
            short4 pk;
            pk.x = bfbits(acc[t][0]); pk.y = bfbits(acc[t][1]);
            pk.z = bfbits(acc[t][2]); pk.w = bfbits(acc[t][3]);
            *(short4*)(out + (size_t)row * HO + t * 16 + kg * 4) = pk;
        }
    }
}

// ---------------- fused: MFMA GEMM layer-1 || CSR fill (4 edges/thread) ----------------

__global__ __launch_bounds__(256) void mf_kernel(const unsigned short* __restrict__ Xb,
                                                 const unsigned short* __restrict__ Wt,
                                                 unsigned short* __restrict__ out,
                                                 const int* __restrict__ src, const int* __restrict__ dst,
                                                 int* __restrict__ cur, int* __restrict__ csr_src) {
    const int tid = threadIdx.x;
    if (blockIdx.x >= MG1_BLOCKS) {
        const int base = (blockIdx.x - MG1_BLOCKS) * 1024;
        int s[4], d[4];
        #pragma unroll
        for (int u = 0; u < 4; u++) {
            int e = base + u * 256 + tid;
            int ec = (e < N_EDGES) ? e : 0;
            s[u] = src[ec];
            d[u] = dst[ec];
        }
        #pragma unroll
        for (int u = 0; u < 4; u++) {
            int e = base + u * 256 + tid;
            if (e < N_EDGES) {
                int pos = atomicAdd(&cur[d[u]], 1);
                csr_src[pos] = s[u];
            }
        }
        return;
    }
    gemm_body<128>(blockIdx.x, Xb, Wt, out);
}

// ---------------- MFMA GEMM (layer 2): out[N,64] ----------------

__global__ __launch_bounds__(256) void mgemm2_kernel(const unsigned short* __restrict__ Xb,
                                                     const unsigned short* __restrict__ Wt,
                                                     unsigned short* __restrict__ out) {
    gemm_body<64>(blockIdx.x, Xb, Wt, out);
}

// ---------------- fused aggregation (bf16 in/out, f32 accum), batch-4 ----------------

template<int F>
__global__ __launch_bounds__(256) void gather_kernel(const unsigned short* __restrict__ xw,
                                                     const float* __restrict__ dinv,
                                                     const int* __restrict__ off,
                                                     const int* __restrict__ deg,
                                                     const int* __restrict__ csr_src,
                                                     const float* __restrict__ bias,
                                                     unsigned short* __restrict__ h) {
    constexpr int LANES = F / 8;        // bf16x8 lanes per node: 16 or 8
    constexpr int NPB = 256 / LANES;
    const int n = blockIdx.x * NPB + threadIdx.x / LANES;
    if (n >= N_NODES) return;
    const int c = threadIdx.x % LANES;

    const float dn = dinv[n];
    float acc[8];
    {
        const bf16x8 v = *(const bf16x8*)(xw + (size_t)n * F + c * 8);
        const float sl = dn * dn;
        #pragma unroll
        for (int i = 0; i < 8; i++) acc[i] = bf2f(v[i]) * sl;
    }

    const int e0 = off[n];
    const int e1 = e0 + deg[n];
    for (int j = e0; j < e1; j += 4) {
        int s[4];
        #pragma unroll
        for (int u = 0; u < 4; u++) {
            const int jj = j + u;
            const int jc = (jj < e1) ? jj : (e1 - 1);
            s[u] = csr_src[jc];
        }
        float w[4]; bf16x8 v[4];
        #pragma unroll
        for (int u = 0; u < 4; u++) {
            w[u] = (j + u < e1) ? dinv[s[u]] * dn : 0.f;
            v[u] = *(const bf16x8*)(xw + (size_t)s[u] * F + c * 8);
        }
        #pragma unroll
        for (int u = 0; u < 4; u++) {
            #pragma unroll
            for (int i = 0; i < 8; i++) acc[i] += bf2f(v[u][i]) * w[u];
        }
    }

    bf16x8 o;
    #pragma unroll
    for (int i = 0; i < 8; i++) o[i] = bfbits(fmaxf(acc[i] + bias[c * 8 + i], 0.f));
    *(bf16x8*)(h + (size_t)n * F + c * 8) = o;
}

// ---------------- head: gelu(h2 @ Wh1 + bh1) @ Wh2 + bh2 -> sigmoid ----------------

__global__ __launch_bounds__(256) void head_kernel(const unsigned short* __restrict__ h2,
                                                   const float* __restrict__ Wh1,
                                                   const float* __restrict__ bh1,
                                                   const float* __restrict__ Wh2,
                                                   const float* __restrict__ bh2,
                                                   float* __restrict__ out) {
    __shared__ float W1s[64 * 16];
    __shared__ float h2s[16 * 64];
    __shared__ float W2s[16];
    __shared__ float b1s[16];
    const int tid = threadIdx.x;
    const int node0 = blockIdx.x * 16;

    ((float4*)W1s)[tid] = ((const float4*)Wh1)[tid];
    if (tid < 16) { W2s[tid] = Wh2[tid]; b1s[tid] = bh1[tid]; }
    if (tid < 128) {                       // 16 nodes x 8 bf16x8-chunks
        int node = node0 + tid / 8;
        int ch = tid % 8;
        if (node < N_NODES) {
            bf16x8 v = *(const bf16x8*)(h2 + (size_t)node * 64 + ch * 8);
            #pragma unroll
            for (int i = 0; i < 8; i++) h2s[(tid / 8) * 64 + ch * 8 + i] = bf2f(v[i]);
        } else {
            #pragma unroll
            for (int i = 0; i < 8; i++) h2s[(tid / 8) * 64 + ch * 8 + i] = 0.f;
        }
    }
    __syncthreads();

    const int l  = tid & 15;
    const int nl = tid >> 4;
    const int node = node0 + nl;

    float s = b1s[l];
    #pragma unroll 8
    for (int k = 0; k < 64; k++)
        s += h2s[nl * 64 + k] * W1s[k * 16 + l];
    float g = 0.5f * s * (1.f + erff(s * 0.70710678118654752f));
    float p = g * W2s[l];
    p += __shfl_xor(p, 1);
    p += __shfl_xor(p, 2);
    p += __shfl_xor(p, 4);
    p += __shfl_xor(p, 8);
    if (l == 0 && node < N_NODES) {
        float z = p + bh2[0];
        out[node] = 1.f / (1.f + expf(-z));
    }
}

// ---------------- launch ----------------

extern "C" void kernel_launch(void* const* d_in, const int* in_sizes, int n_in,
                              void* d_out, int out_size, void* d_ws, size_t ws_size,
                              hipStream_t stream) {
    const float* x   = (const float*)d_in[0];
    const int*   ei  = (const int*)d_in[1];
    const float* W1  = (const float*)d_in[2];
    const float* b1  = (const float*)d_in[3];
    const float* W2  = (const float*)d_in[4];
    const float* b2  = (const float*)d_in[5];
    const float* Wh1 = (const float*)d_in[6];
    const float* bh1 = (const float*)d_in[7];
    const float* Wh2 = (const float*)d_in[8];
    const float* bh2 = (const float*)d_in[9];
    float* out = (float*)d_out;

    const int* srcA = ei;             // edge_index[0]
    const int* dstA = ei + N_EDGES;   // edge_index[1]

    char* ws = (char*)d_ws;
    const size_t MB = 1u << 20;
    float* dinv    = (float*)(ws);                    // N f32
    int*   deg     = (int*)  (ws + MB / 2);           // N i32 (+1 counter)
    int*   counter = deg + N_NODES;                   // 1 i32
    int*   off     = (int*)  (ws + MB);               // N i32
    int*   cur     = (int*)  (ws + MB + MB / 2);      // N i32
    int*   csr_src = (int*)  (ws + 2 * MB);           // E i32 (2.4MB)
    unsigned short* Wt1 = (unsigned short*)(ws + 7 * MB);            // 128x128 bf16
    unsigned short* Wt2 = Wt1 + 128 * 128;                           // 64x128 bf16
    unsigned short* bufA = (unsigned short*)(ws + 8 * MB);           // xw1 (N x 128 bf16, 25.6MB)
    unsigned short* bufB = (unsigned short*)(ws + 34 * MB);          // h1  (N x 128 bf16)
    unsigned short* Xb   = (unsigned short*)(ws + 60 * MB);          // X bf16 (N x 128, 25.6MB)
    unsigned short* xw2  = bufA;                                     // N x 64 bf16
    unsigned short* h2   = bufA + (size_t)N_NODES * F2;              // N x 64 bf16

    // zero deg+counter; (deg || convw || convX); prep; (mgemm1 || fill)
    hipMemsetAsync(deg, 0, (N_NODES + 1) * sizeof(int), stream);
    dc_kernel<<<DEG_BLOCKS + CONVW_BLOCKS + XB_BLOCKS, 256, 0, stream>>>(
        dstA, deg, W1, W2, Wt1, Wt2, x, Xb);
    prep_kernel<<<(N_NODES + 255) / 256, 256, 0, stream>>>(deg, counter, dinv, off, cur);
    mf_kernel<<<MG1_BLOCKS + FILL_BLOCKS, 256, 0, stream>>>(Xb, Wt1, bufA, srcA, dstA, cur, csr_src);

    // layer 1 aggregation
    gather_kernel<128><<<(N_NODES * 16 + 255) / 256, 256, 0, stream>>>(bufA, dinv, off, deg, csr_src, b1, bufB);

    // layer 2
    mgemm2_kernel<<<MG1_BLOCKS, 256, 0, stream>>>(bufB, Wt2, xw2);
    gather_kernel<64><<<(N_NODES * 8 + 255) / 256, 256, 0, stream>>>(xw2, dinv, off, deg, csr_src, b2, h2);

    // head
    head_kernel<<<(N_NODES + 15) / 16, 256, 0, stream>>>(h2, Wh1, bh1, Wh2, bh2, out);
}

// Round 14
// 202.637 us; speedup vs baseline: 1.1060x; 1.0922x over previous
//
#include <hip/hip_runtime.h>
#include <hip/hip_bf16.h>
#include <math.h>

#define N_NODES 100000
#define N_EDGES 600000
#define F1 128   // conv1 width
#define F2 64    // conv2 width

#define DEG_BLOCKS   ((N_EDGES + 255) / 256)           // 2344
#define CONVW_ELEMS  (128 * 128 + 128 * 64)
#define CONVW_BLOCKS ((CONVW_ELEMS + 255) / 256)       // 96
#define MG1_BLOCKS   ((N_NODES + 63) / 64)             // 1563
#define GG_BLOCKS    (N_NODES / 16)                    // 6250 (exact)

typedef __attribute__((ext_vector_type(8))) short bf16x8;
typedef __attribute__((ext_vector_type(4))) float f32x4;

__device__ inline short bfbits(float x) {
    __hip_bfloat16 h = __float2bfloat16(x);
    return *reinterpret_cast<short*>(&h);
}
__device__ inline float bf2f(short u) {
    unsigned int x = ((unsigned int)(unsigned short)u) << 16;
    return __uint_as_float(x);
}

// ---------------- fused: degree count || weight conversion ----------------

__global__ __launch_bounds__(256) void dc_kernel(const int* __restrict__ dst, int* __restrict__ deg,
                                                 const float* __restrict__ W1, const float* __restrict__ W2,
                                                 unsigned short* __restrict__ Wt1, unsigned short* __restrict__ Wt2) {
    if (blockIdx.x < DEG_BLOCKS) {
        int e = blockIdx.x * 256 + threadIdx.x;
        if (e < N_EDGES) atomicAdd(&deg[dst[e]], 1);
    } else {
        int i = (blockIdx.x - DEG_BLOCKS) * 256 + threadIdx.x;
        if (i < 128 * 128) {
            int k = i / 128, n = i % 128;
            Wt1[n * 128 + k] = (unsigned short)bfbits(W1[i]);
        } else if (i < CONVW_ELEMS) {
            int j = i - 128 * 128;
            int k = j / 64, n = j % 64;
            Wt2[n * 128 + k] = (unsigned short)bfbits(W2[j]);
        }
    }
}

// ---------------- fused: dinv + region alloc (wave scan + one atomic) + cur init ----------

__global__ void prep_kernel(const int* __restrict__ deg, int* __restrict__ counter,
                            float* __restrict__ dinv, int* __restrict__ off,
                            int* __restrict__ cur) {
    int i = blockIdx.x * blockDim.x + threadIdx.x;
    int d = (i < N_NODES) ? deg[i] : 0;
    if (i < N_NODES) dinv[i] = rsqrtf((float)(d + 1));   // +1 self-loop
    int incl = d;
    #pragma unroll
    for (int o = 1; o < 64; o <<= 1) {
        int v = __shfl_up(incl, o);
        if ((threadIdx.x & 63) >= o) incl += v;
    }
    int base = 0;
    if ((threadIdx.x & 63) == 63) base = atomicAdd(counter, incl);
    base = __shfl(base, 63);
    if (i < N_NODES) {
        int o = base + incl - d;
        off[i] = o;
        cur[i] = o;
    }
}

// ---------------- fused: MFMA GEMM layer-1 (C^T operand swap) || CSR fill ----------------

__global__ __launch_bounds__(256) void mf_kernel(const float* __restrict__ X,
                                                 const unsigned short* __restrict__ Wt,
                                                 unsigned short* __restrict__ out,
                                                 const int* __restrict__ src, const int* __restrict__ dst,
                                                 int* __restrict__ cur, int* __restrict__ csr_src) {
    const int tid = threadIdx.x;
    if (blockIdx.x >= MG1_BLOCKS) {
        int e = (blockIdx.x - MG1_BLOCKS) * 256 + tid;
        if (e < N_EDGES) {
            int s = src[e], d = dst[e];
            int pos = atomicAdd(&cur[d], 1);
            csr_src[pos] = s;
        }
        return;
    }

    constexpr int NT = 128 / 16;
    const int wid = tid >> 6;
    const int l   = tid & 63;
    const int l16 = l & 15;
    const int kg  = l >> 4;          // 0..3

    const int row = blockIdx.x * 64 + wid * 16 + l16;
    const int rowc = (row < N_NODES) ? row : (N_NODES - 1);

    bf16x8 a[4];
    const float* xp = X + (size_t)rowc * 128 + kg * 8;
    #pragma unroll
    for (int ks = 0; ks < 4; ks++) {
        const float4 v0 = *(const float4*)(xp + ks * 32);
        const float4 v1 = *(const float4*)(xp + ks * 32 + 4);
        bf16x8 t;
        t[0] = bfbits(v0.x); t[1] = bfbits(v0.y); t[2] = bfbits(v0.z); t[3] = bfbits(v0.w);
        t[4] = bfbits(v1.x); t[5] = bfbits(v1.y); t[6] = bfbits(v1.z); t[7] = bfbits(v1.w);
        a[ks] = t;
    }

    f32x4 acc[NT];
    #pragma unroll
    for (int t = 0; t < NT; t++) acc[t] = (f32x4){0.f, 0.f, 0.f, 0.f};

    #pragma unroll
    for (int t = 0; t < NT; t++) {
        const unsigned short* wp = Wt + (size_t)(t * 16 + l16) * 128 + kg * 8;
        #pragma unroll
        for (int ks = 0; ks < 4; ks++) {
            bf16x8 bb = *(const bf16x8*)(wp + ks * 32);
            acc[t] = __builtin_amdgcn_mfma_f32_16x16x32_bf16(bb, a[ks], acc[t], 0, 0, 0);
        }
    }

    // C^T layout: this thread owns row `row`, cols {t*16 + kg*4 + r}
    if (row < N_NODES) {
        #pragma unroll
        for (int t = 0; t < NT; t++) {
            short4 pk;
            pk.x = bfbits(acc[t][0]); pk.y = bfbits(acc[t][1]);
            pk.z = bfbits(acc[t][2]); pk.w = bfbits(acc[t][3]);
            *(short4*)(out + (size_t)row * 128 + t * 16 + kg * 4) = pk;
        }
    }
}

// ---------------- fused: gather layer-1 + MFMA layer-2 GEMM ----------------
// Block = 256 thr, 16 nodes. Phase 1: gather h1 rows (relu(sum+b1)) -> LDS (bf16,
// XOR-swizzled). Phase 2: xw2[16x64] = H[16x128] @ W2 via 4 waves x 4 MFMA (C^T swap).

__global__ __launch_bounds__(256) void gg_kernel(const unsigned short* __restrict__ xw,
                                                 const float* __restrict__ dinv,
                                                 const int* __restrict__ off,
                                                 const int* __restrict__ deg,
                                                 const int* __restrict__ csr_src,
                                                 const float* __restrict__ bias,
                                                 const unsigned short* __restrict__ Wt2,
                                                 unsigned short* __restrict__ xw2) {
    __shared__ unsigned short H[16 * 128];   // 4KB
    char* Hb = (char*)H;
    const int tid = threadIdx.x;
    const int nl = tid >> 4;          // node_local 0..15
    const int c  = tid & 15;          // bf16x8 chunk 0..15
    const int n  = blockIdx.x * 16 + nl;   // grid exact: always < N_NODES

    const float dn = dinv[n];
    float acc[8];
    {
        const bf16x8 v = *(const bf16x8*)(xw + (size_t)n * 128 + c * 8);
        const float sl = dn * dn;
        #pragma unroll
        for (int i = 0; i < 8; i++) acc[i] = bf2f(v[i]) * sl;
    }
    const int e0 = off[n];
    const int e1 = e0 + deg[n];
    for (int j = e0; j < e1; j += 4) {
        int s[4];
        #pragma unroll
        for (int u = 0; u < 4; u++) {
            const int jj = j + u;
            const int jc = (jj < e1) ? jj : (e1 - 1);
            s[u] = csr_src[jc];
        }
        float w[4]; bf16x8 v[4];
        #pragma unroll
        for (int u = 0; u < 4; u++) {
            w[u] = (j + u < e1) ? dinv[s[u]] * dn : 0.f;
            v[u] = *(const bf16x8*)(xw + (size_t)s[u] * 128 + c * 8);
        }
        #pragma unroll
        for (int u = 0; u < 4; u++) {
            #pragma unroll
            for (int i = 0; i < 8; i++) acc[i] += bf2f(v[u][i]) * w[u];
        }
    }
    bf16x8 o;
    #pragma unroll
    for (int i = 0; i < 8; i++) o[i] = bfbits(fmaxf(acc[i] + bias[c * 8 + i], 0.f));
    *(bf16x8*)(Hb + nl * 256 + ((c * 16) ^ ((nl & 7) << 4))) = o;
    __syncthreads();

    // phase 2: wave w -> col-tile w of xw2
    const int w   = tid >> 6;
    const int l   = tid & 63;
    const int l16 = l & 15;
    const int kg  = l >> 4;
    bf16x8 a[4];
    #pragma unroll
    for (int ks = 0; ks < 4; ks++)
        a[ks] = *(const bf16x8*)(Hb + l16 * 256 + ((kg * 16 + ks * 64) ^ ((l16 & 7) << 4)));
    const unsigned short* wp = Wt2 + (size_t)(w * 16 + l16) * 128 + kg * 8;
    f32x4 acc2 = (f32x4){0.f, 0.f, 0.f, 0.f};
    #pragma unroll
    for (int ks = 0; ks < 4; ks++) {
        bf16x8 bb = *(const bf16x8*)(wp + ks * 32);
        acc2 = __builtin_amdgcn_mfma_f32_16x16x32_bf16(bb, a[ks], acc2, 0, 0, 0);
    }
    // C^T: node = blk*16 + l16, cols {w*16 + kg*4 + r}
    const int node = blockIdx.x * 16 + l16;
    short4 pk;
    pk.x = bfbits(acc2[0]); pk.y = bfbits(acc2[1]);
    pk.z = bfbits(acc2[2]); pk.w = bfbits(acc2[3]);
    *(short4*)(xw2 + (size_t)node * 64 + w * 16 + kg * 4) = pk;
}

// ---------------- fused aggregation layer-2 (bf16 in/out, f32 accum), batch-4 ----------------

template<int F>
__global__ __launch_bounds__(256) void gather_kernel(const unsigned short* __restrict__ xw,
                                                     const float* __restrict__ dinv,
                                                     const int* __restrict__ off,
                                                     const int* __restrict__ deg,
                                                     const int* __restrict__ csr_src,
                                                     const float* __restrict__ bias,
                                                     unsigned short* __restrict__ h) {
    constexpr int LANES = F / 8;
    constexpr int NPB = 256 / LANES;
    const int n = blockIdx.x * NPB + threadIdx.x / LANES;
    if (n >= N_NODES) return;
    const int c = threadIdx.x % LANES;

    const float dn = dinv[n];
    float acc[8];
    {
        const bf16x8 v = *(const bf16x8*)(xw + (size_t)n * F + c * 8);
        const float sl = dn * dn;
        #pragma unroll
        for (int i = 0; i < 8; i++) acc[i] = bf2f(v[i]) * sl;
    }

    const int e0 = off[n];
    const int e1 = e0 + deg[n];
    for (int j = e0; j < e1; j += 4) {
        int s[4];
        #pragma unroll
        for (int u = 0; u < 4; u++) {
            const int jj = j + u;
            const int jc = (jj < e1) ? jj : (e1 - 1);
            s[u] = csr_src[jc];
        }
        float w[4]; bf16x8 v[4];
        #pragma unroll
        for (int u = 0; u < 4; u++) {
            w[u] = (j + u < e1) ? dinv[s[u]] * dn : 0.f;
            v[u] = *(const bf16x8*)(xw + (size_t)s[u] * F + c * 8);
        }
        #pragma unroll
        for (int u = 0; u < 4; u++) {
            #pragma unroll
            for (int i = 0; i < 8; i++) acc[i] += bf2f(v[u][i]) * w[u];
        }
    }

    bf16x8 o;
    #pragma unroll
    for (int i = 0; i < 8; i++) o[i] = bfbits(fmaxf(acc[i] + bias[c * 8 + i], 0.f));
    *(bf16x8*)(h + (size_t)n * F + c * 8) = o;
}

// ---------------- head: gelu(h2 @ Wh1 + bh1) @ Wh2 + bh2 -> sigmoid ----------------

__global__ __launch_bounds__(256) void head_kernel(const unsigned short* __restrict__ h2,
                                                   const float* __restrict__ Wh1,
                                                   const float* __restrict__ bh1,
                                                   const float* __restrict__ Wh2,
                                                   const float* __restrict__ bh2,
                                                   float* __restrict__ out) {
    __shared__ float W1s[64 * 16];
    __shared__ float h2s[16 * 64];
    __shared__ float W2s[16];
    __shared__ float b1s[16];
    const int tid = threadIdx.x;
    const int node0 = blockIdx.x * 16;

    ((float4*)W1s)[tid] = ((const float4*)Wh1)[tid];
    if (tid < 16) { W2s[tid] = Wh2[tid]; b1s[tid] = bh1[tid]; }
    if (tid < 128) {
        int node = node0 + tid / 8;
        int ch = tid % 8;
        if (node < N_NODES) {
            bf16x8 v = *(const bf16x8*)(h2 + (size_t)node * 64 + ch * 8);
            #pragma unroll
            for (int i = 0; i < 8; i++) h2s[(tid / 8) * 64 + ch * 8 + i] = bf2f(v[i]);
        } else {
            #pragma unroll
            for (int i = 0; i < 8; i++) h2s[(tid / 8) * 64 + ch * 8 + i] = 0.f;
        }
    }
    __syncthreads();

    const int l  = tid & 15;
    const int nl = tid >> 4;
    const int node = node0 + nl;

    float s = b1s[l];
    #pragma unroll 8
    for (int k = 0; k < 64; k++)
        s += h2s[nl * 64 + k] * W1s[k * 16 + l];
    float g = 0.5f * s * (1.f + erff(s * 0.70710678118654752f));
    float p = g * W2s[l];
    p += __shfl_xor(p, 1);
    p += __shfl_xor(p, 2);
    p += __shfl_xor(p, 4);
    p += __shfl_xor(p, 8);
    if (l == 0 && node < N_NODES) {
        float z = p + bh2[0];
        out[node] = 1.f / (1.f + expf(-z));
    }
}

// ---------------- launch ----------------

extern "C" void kernel_launch(void* const* d_in, const int* in_sizes, int n_in,
                              void* d_out, int out_size, void* d_ws, size_t ws_size,
                              hipStream_t stream) {
    const float* x   = (const float*)d_in[0];
    const int*   ei  = (const int*)d_in[1];
    const float* W1  = (const float*)d_in[2];
    const float* b1  = (const float*)d_in[3];
    const float* W2  = (const float*)d_in[4];
    const float* b2  = (const float*)d_in[5];
    const float* Wh1 = (const float*)d_in[6];
    const float* bh1 = (const float*)d_in[7];
    const float* Wh2 = (const float*)d_in[8];
    const float* bh2 = (const float*)d_in[9];
    float* out = (float*)d_out;

    const int* srcA = ei;             // edge_index[0]
    const int* dstA = ei + N_EDGES;   // edge_index[1]

    char* ws = (char*)d_ws;
    const size_t MB = 1u << 20;
    float* dinv    = (float*)(ws);                    // N f32
    int*   deg     = (int*)  (ws + MB / 2);           // N i32 (+1 counter)
    int*   counter = deg + N_NODES;                   // 1 i32
    int*   off     = (int*)  (ws + MB);               // N i32
    int*   cur     = (int*)  (ws + MB + MB / 2);      // N i32
    int*   csr_src = (int*)  (ws + 2 * MB);           // E i32 (2.4MB)
    unsigned short* Wt1 = (unsigned short*)(ws + 7 * MB);            // 128x128 bf16
    unsigned short* Wt2 = Wt1 + 128 * 128;                           // 64x128 bf16
    unsigned short* bufA = (unsigned short*)(ws + 8 * MB);           // xw1 (N x 128 bf16, 25.6MB)
    unsigned short* xw2  = (unsigned short*)(ws + 34 * MB);          // N x 64 bf16 (12.8MB)
    unsigned short* h2   = xw2 + (size_t)N_NODES * F2;               // N x 64 bf16

    // zero deg+counter; (deg || convw); prep; (mgemm1 || fill)
    hipMemsetAsync(deg, 0, (N_NODES + 1) * sizeof(int), stream);
    dc_kernel<<<DEG_BLOCKS + CONVW_BLOCKS, 256, 0, stream>>>(dstA, deg, W1, W2, Wt1, Wt2);
    prep_kernel<<<(N_NODES + 255) / 256, 256, 0, stream>>>(deg, counter, dinv, off, cur);
    mf_kernel<<<MG1_BLOCKS + DEG_BLOCKS, 256, 0, stream>>>(x, Wt1, bufA, srcA, dstA, cur, csr_src);

    // layer-1 aggregation + layer-2 GEMM fused
    gg_kernel<<<GG_BLOCKS, 256, 0, stream>>>(bufA, dinv, off, deg, csr_src, b1, Wt2, xw2);

    // layer-2 aggregation
    gather_kernel<64><<<(N_NODES * 8 + 255) / 256, 256, 0, stream>>>(xw2, dinv, off, deg, csr_src, b2, h2);

    // head
    head_kernel<<<(N_NODES + 15) / 16, 256, 0, stream>>>(h2, Wh1, bh1, Wh2, bh2, out);
}

// Round 15
// 168.008 us; speedup vs baseline: 1.3340x; 1.2061x over previous
//
#include <hip/hip_runtime.h>
#include <hip/hip_bf16.h>
#include <math.h>

#define N_NODES 100000
#define N_EDGES 600000
#define F1 128   // conv1 width
#define F2 64    // conv2 width

#define DEG_BLOCKS   ((N_EDGES + 255) / 256)           // 2344
#define CONVW_ELEMS  (128 * 128 + 128 * 64)
#define CONVW_BLOCKS ((CONVW_ELEMS + 255) / 256)       // 96
#define MG1_BLOCKS   ((N_NODES + 63) / 64)             // 1563
#define GG_BLOCKS    (N_NODES / 16)                    // 6250 (exact)
#define GH_BLOCKS    (N_NODES / 32)                    // 3125 (exact)

typedef __attribute__((ext_vector_type(8))) short bf16x8;
typedef __attribute__((ext_vector_type(4))) float f32x4;

__device__ inline short bfbits(float x) {
    __hip_bfloat16 h = __float2bfloat16(x);
    return *reinterpret_cast<short*>(&h);
}
__device__ inline float bf2f(short u) {
    unsigned int x = ((unsigned int)(unsigned short)u) << 16;
    return __uint_as_float(x);
}

// ---------------- fused: degree+rank || weight conversion ----------------
// rank[e] = old count = e's slot within its dst bucket (free from the deg atomic).

__global__ __launch_bounds__(256) void dc_kernel(const int* __restrict__ dst, int* __restrict__ deg,
                                                 int* __restrict__ rank,
                                                 const float* __restrict__ W1, const float* __restrict__ W2,
                                                 unsigned short* __restrict__ Wt1, unsigned short* __restrict__ Wt2) {
    if (blockIdx.x < DEG_BLOCKS) {
        int e = blockIdx.x * 256 + threadIdx.x;
        if (e < N_EDGES) rank[e] = atomicAdd(&deg[dst[e]], 1);
    } else {
        int i = (blockIdx.x - DEG_BLOCKS) * 256 + threadIdx.x;
        if (i < 128 * 128) {
            int k = i / 128, n = i % 128;
            Wt1[n * 128 + k] = (unsigned short)bfbits(W1[i]);
        } else if (i < CONVW_ELEMS) {
            int j = i - 128 * 128;
            int k = j / 64, n = j % 64;
            Wt2[n * 128 + k] = (unsigned short)bfbits(W2[j]);
        }
    }
}

// ---------------- fused: dinv + region alloc (wave scan + one atomic) ----------

__global__ void prep_kernel(const int* __restrict__ deg, int* __restrict__ counter,
                            float* __restrict__ dinv, int* __restrict__ off) {
    int i = blockIdx.x * blockDim.x + threadIdx.x;
    int d = (i < N_NODES) ? deg[i] : 0;
    if (i < N_NODES) dinv[i] = rsqrtf((float)(d + 1));   // +1 self-loop
    int incl = d;
    #pragma unroll
    for (int o = 1; o < 64; o <<= 1) {
        int v = __shfl_up(incl, o);
        if ((threadIdx.x & 63) >= o) incl += v;
    }
    int base = 0;
    if ((threadIdx.x & 63) == 63) base = atomicAdd(counter, incl);
    base = __shfl(base, 63);
    if (i < N_NODES) off[i] = base + incl - d;
}

// ---------------- fused: MFMA GEMM layer-1 (C^T operand swap) || CSR fill (atomic-free) ----

__global__ __launch_bounds__(256) void mf_kernel(const float* __restrict__ X,
                                                 const unsigned short* __restrict__ Wt,
                                                 unsigned short* __restrict__ out,
                                                 const int* __restrict__ src, const int* __restrict__ dst,
                                                 const int* __restrict__ rank, const int* __restrict__ off,
                                                 int* __restrict__ csr_src) {
    const int tid = threadIdx.x;
    if (blockIdx.x >= MG1_BLOCKS) {
        int e = (blockIdx.x - MG1_BLOCKS) * 256 + tid;
        if (e < N_EDGES) {
            int s = src[e], d = dst[e];
            int pos = off[d] + rank[e];
            csr_src[pos] = s;
        }
        return;
    }

    constexpr int NT = 128 / 16;
    const int wid = tid >> 6;
    const int l   = tid & 63;
    const int l16 = l & 15;
    const int kg  = l >> 4;          // 0..3

    const int row = blockIdx.x * 64 + wid * 16 + l16;
    const int rowc = (row < N_NODES) ? row : (N_NODES - 1);

    bf16x8 a[4];
    const float* xp = X + (size_t)rowc * 128 + kg * 8;
    #pragma unroll
    for (int ks = 0; ks < 4; ks++) {
        const float4 v0 = *(const float4*)(xp + ks * 32);
        const float4 v1 = *(const float4*)(xp + ks * 32 + 4);
        bf16x8 t;
        t[0] = bfbits(v0.x); t[1] = bfbits(v0.y); t[2] = bfbits(v0.z); t[3] = bfbits(v0.w);
        t[4] = bfbits(v1.x); t[5] = bfbits(v1.y); t[6] = bfbits(v1.z); t[7] = bfbits(v1.w);
        a[ks] = t;
    }

    f32x4 acc[NT];
    #pragma unroll
    for (int t = 0; t < NT; t++) acc[t] = (f32x4){0.f, 0.f, 0.f, 0.f};

    #pragma unroll
    for (int t = 0; t < NT; t++) {
        const unsigned short* wp = Wt + (size_t)(t * 16 + l16) * 128 + kg * 8;
        #pragma unroll
        for (int ks = 0; ks < 4; ks++) {
            bf16x8 bb = *(const bf16x8*)(wp + ks * 32);
            acc[t] = __builtin_amdgcn_mfma_f32_16x16x32_bf16(bb, a[ks], acc[t], 0, 0, 0);
        }
    }

    // C^T layout: this thread owns row `row`, cols {t*16 + kg*4 + r}
    if (row < N_NODES) {
        #pragma unroll
        for (int t = 0; t < NT; t++) {
            short4 pk;
            pk.x = bfbits(acc[t][0]); pk.y = bfbits(acc[t][1]);
            pk.z = bfbits(acc[t][2]); pk.w = bfbits(acc[t][3]);
            *(short4*)(out + (size_t)row * 128 + t * 16 + kg * 4) = pk;
        }
    }
}

// ---------------- fused: gather layer-1 + MFMA layer-2 GEMM ----------------

__global__ __launch_bounds__(256) void gg_kernel(const unsigned short* __restrict__ xw,
                                                 const float* __restrict__ dinv,
                                                 const int* __restrict__ off,
                                                 const int* __restrict__ deg,
                                                 const int* __restrict__ csr_src,
                                                 const float* __restrict__ bias,
                                                 const unsigned short* __restrict__ Wt2,
                                                 unsigned short* __restrict__ xw2) {
    __shared__ unsigned short H[16 * 128];   // 4KB
    char* Hb = (char*)H;
    const int tid = threadIdx.x;
    const int nl = tid >> 4;          // node_local 0..15
    const int c  = tid & 15;          // bf16x8 chunk 0..15
    const int n  = blockIdx.x * 16 + nl;   // grid exact: always < N_NODES

    const float dn = dinv[n];
    float acc[8];
    {
        const bf16x8 v = *(const bf16x8*)(xw + (size_t)n * 128 + c * 8);
        const float sl = dn * dn;
        #pragma unroll
        for (int i = 0; i < 8; i++) acc[i] = bf2f(v[i]) * sl;
    }
    const int e0 = off[n];
    const int e1 = e0 + deg[n];
    for (int j = e0; j < e1; j += 4) {
        int s[4];
        #pragma unroll
        for (int u = 0; u < 4; u++) {
            const int jj = j + u;
            const int jc = (jj < e1) ? jj : (e1 - 1);
            s[u] = csr_src[jc];
        }
        float w[4]; bf16x8 v[4];
        #pragma unroll
        for (int u = 0; u < 4; u++) {
            w[u] = (j + u < e1) ? dinv[s[u]] * dn : 0.f;
            v[u] = *(const bf16x8*)(xw + (size_t)s[u] * 128 + c * 8);
        }
        #pragma unroll
        for (int u = 0; u < 4; u++) {
            #pragma unroll
            for (int i = 0; i < 8; i++) acc[i] += bf2f(v[u][i]) * w[u];
        }
    }
    bf16x8 o;
    #pragma unroll
    for (int i = 0; i < 8; i++) o[i] = bfbits(fmaxf(acc[i] + bias[c * 8 + i], 0.f));
    *(bf16x8*)(Hb + nl * 256 + ((c * 16) ^ ((nl & 7) << 4))) = o;
    __syncthreads();

    // phase 2: wave w -> col-tile w of xw2
    const int w   = tid >> 6;
    const int l   = tid & 63;
    const int l16 = l & 15;
    const int kg  = l >> 4;
    bf16x8 a[4];
    #pragma unroll
    for (int ks = 0; ks < 4; ks++)
        a[ks] = *(const bf16x8*)(Hb + l16 * 256 + ((kg * 16 + ks * 64) ^ ((l16 & 7) << 4)));
    const unsigned short* wp = Wt2 + (size_t)(w * 16 + l16) * 128 + kg * 8;
    f32x4 acc2 = (f32x4){0.f, 0.f, 0.f, 0.f};
    #pragma unroll
    for (int ks = 0; ks < 4; ks++) {
        bf16x8 bb = *(const bf16x8*)(wp + ks * 32);
        acc2 = __builtin_amdgcn_mfma_f32_16x16x32_bf16(bb, a[ks], acc2, 0, 0, 0);
    }
    const int node = blockIdx.x * 16 + l16;
    short4 pk;
    pk.x = bfbits(acc2[0]); pk.y = bfbits(acc2[1]);
    pk.z = bfbits(acc2[2]); pk.w = bfbits(acc2[3]);
    *(short4*)(xw2 + (size_t)node * 64 + w * 16 + kg * 4) = pk;
}

// ---------------- fused: gather layer-2 + head ----------------
// Block = 256 thr, 32 nodes. Phase 1: gather h2 (8 lanes/node) -> LDS (bf16-rounded,
// widened to f32, padded stride 68). Phase 2: proven head structure, 16 lanes/node x 2 sets.

__global__ __launch_bounds__(256) void gh_kernel(const unsigned short* __restrict__ xw2,
                                                 const float* __restrict__ dinv,
                                                 const int* __restrict__ off,
                                                 const int* __restrict__ deg,
                                                 const int* __restrict__ csr_src,
                                                 const float* __restrict__ b2,
                                                 const float* __restrict__ Wh1,
                                                 const float* __restrict__ bh1,
                                                 const float* __restrict__ Wh2,
                                                 const float* __restrict__ bh2,
                                                 float* __restrict__ out) {
    __shared__ float h2s[32 * 68];   // 8.5KB, padded stride
    __shared__ float W1s[64 * 16];
    __shared__ float W2s[16];
    __shared__ float b1s[16];
    const int tid = threadIdx.x;

    ((float4*)W1s)[tid] = ((const float4*)Wh1)[tid];     // 1024 floats
    if (tid < 16) { W2s[tid] = Wh2[tid]; b1s[tid] = bh1[tid]; }

    // phase 1: gather (8 lanes per node, 32 nodes)
    const int nl = tid >> 3;          // 0..31
    const int c  = tid & 7;           // 0..7
    const int n  = blockIdx.x * 32 + nl;   // grid exact

    const float dn = dinv[n];
    float acc[8];
    {
        const bf16x8 v = *(const bf16x8*)(xw2 + (size_t)n * 64 + c * 8);
        const float sl = dn * dn;
        #pragma unroll
        for (int i = 0; i < 8; i++) acc[i] = bf2f(v[i]) * sl;
    }
    const int e0 = off[n];
    const int e1 = e0 + deg[n];
    for (int j = e0; j < e1; j += 4) {
        int s[4];
        #pragma unroll
        for (int u = 0; u < 4; u++) {
            const int jj = j + u;
            const int jc = (jj < e1) ? jj : (e1 - 1);
            s[u] = csr_src[jc];
        }
        float w[4]; bf16x8 v[4];
        #pragma unroll
        for (int u = 0; u < 4; u++) {
            w[u] = (j + u < e1) ? dinv[s[u]] * dn : 0.f;
            v[u] = *(const bf16x8*)(xw2 + (size_t)s[u] * 64 + c * 8);
        }
        #pragma unroll
        for (int u = 0; u < 4; u++) {
            #pragma unroll
            for (int i = 0; i < 8; i++) acc[i] += bf2f(v[u][i]) * w[u];
        }
    }
    // bf16 round-trip (bit-identical to prior global h2 path), widen to f32 in LDS
    float4 f0, f1;
    f0.x = bf2f(bfbits(fmaxf(acc[0] + b2[c * 8 + 0], 0.f)));
    f0.y = bf2f(bfbits(fmaxf(acc[1] + b2[c * 8 + 1], 0.f)));
    f0.z = bf2f(bfbits(fmaxf(acc[2] + b2[c * 8 + 2], 0.f)));
    f0.w = bf2f(bfbits(fmaxf(acc[3] + b2[c * 8 + 3], 0.f)));
    f1.x = bf2f(bfbits(fmaxf(acc[4] + b2[c * 8 + 4], 0.f)));
    f1.y = bf2f(bfbits(fmaxf(acc[5] + b2[c * 8 + 5], 0.f)));
    f1.z = bf2f(bfbits(fmaxf(acc[6] + b2[c * 8 + 6], 0.f)));
    f1.w = bf2f(bfbits(fmaxf(acc[7] + b2[c * 8 + 7], 0.f)));
    *(float4*)&h2s[nl * 68 + c * 8]     = f0;
    *(float4*)&h2s[nl * 68 + c * 8 + 4] = f1;
    __syncthreads();

    // phase 2: head, 16 lanes/node, two node-sets
    const int l  = tid & 15;
    const int nn = tid >> 4;          // 0..15
    #pragma unroll
    for (int ss = 0; ss < 2; ss++) {
        const int node_l = ss * 16 + nn;
        float s = b1s[l];
        #pragma unroll 8
        for (int k = 0; k < 64; k++)
            s += h2s[node_l * 68 + k] * W1s[k * 16 + l];
        float g = 0.5f * s * (1.f + erff(s * 0.70710678118654752f));
        float p = g * W2s[l];
        p += __shfl_xor(p, 1);
        p += __shfl_xor(p, 2);
        p += __shfl_xor(p, 4);
        p += __shfl_xor(p, 8);
        if (l == 0) {
            const float z = p + bh2[0];
            out[blockIdx.x * 32 + node_l] = 1.f / (1.f + expf(-z));
        }
    }
}

// ---------------- launch ----------------

extern "C" void kernel_launch(void* const* d_in, const int* in_sizes, int n_in,
                              void* d_out, int out_size, void* d_ws, size_t ws_size,
                              hipStream_t stream) {
    const float* x   = (const float*)d_in[0];
    const int*   ei  = (const int*)d_in[1];
    const float* W1  = (const float*)d_in[2];
    const float* b1  = (const float*)d_in[3];
    const float* W2  = (const float*)d_in[4];
    const float* b2  = (const float*)d_in[5];
    const float* Wh1 = (const float*)d_in[6];
    const float* bh1 = (const float*)d_in[7];
    const float* Wh2 = (const float*)d_in[8];
    const float* bh2 = (const float*)d_in[9];
    float* out = (float*)d_out;

    const int* srcA = ei;             // edge_index[0]
    const int* dstA = ei + N_EDGES;   // edge_index[1]

    char* ws = (char*)d_ws;
    const size_t MB = 1u << 20;
    float* dinv    = (float*)(ws);                    // N f32
    int*   deg     = (int*)  (ws + MB / 2);           // N i32 (+1 counter)
    int*   counter = deg + N_NODES;                   // 1 i32
    int*   off     = (int*)  (ws + MB);               // N i32
    int*   rank    = (int*)  (ws + MB + MB / 2);      // E i32 (2.4MB)
    int*   csr_src = (int*)  (ws + 4 * MB);           // E i32 (2.4MB)
    unsigned short* Wt1 = (unsigned short*)(ws + 7 * MB);            // 128x128 bf16
    unsigned short* Wt2 = Wt1 + 128 * 128;                           // 64x128 bf16
    unsigned short* bufA = (unsigned short*)(ws + 8 * MB);           // xw1 (N x 128 bf16, 25.6MB)
    unsigned short* xw2  = (unsigned short*)(ws + 34 * MB);          // N x 64 bf16 (12.8MB)

    // zero deg+counter; (deg/rank || convw); prep; (mgemm1 || fill)
    hipMemsetAsync(deg, 0, (N_NODES + 1) * sizeof(int), stream);
    dc_kernel<<<DEG_BLOCKS + CONVW_BLOCKS, 256, 0, stream>>>(dstA, deg, rank, W1, W2, Wt1, Wt2);
    prep_kernel<<<(N_NODES + 255) / 256, 256, 0, stream>>>(deg, counter, dinv, off);
    mf_kernel<<<MG1_BLOCKS + DEG_BLOCKS, 256, 0, stream>>>(x, Wt1, bufA, srcA, dstA, rank, off, csr_src);

    // layer-1 aggregation + layer-2 GEMM fused
    gg_kernel<<<GG_BLOCKS, 256, 0, stream>>>(bufA, dinv, off, deg, csr_src, b1, Wt2, xw2);

    // layer-2 aggregation + head fused
    gh_kernel<<<GH_BLOCKS, 256, 0, stream>>>(xw2, dinv, off, deg, csr_src, b2,
                                             Wh1, bh1, Wh2, bh2, out);
}